// Round 1
// baseline (684.679 us; speedup 1.0000x reference)
//
#include <hip/hip_runtime.h>

// ---------------------------------------------------------------------------
// Problem constants
// ---------------------------------------------------------------------------
#define B_N 16384
#define T_N 64
#define H_N 64
// output layout (floats): X_out [B,T], T10 [B], M0 [B], out [B,T,H], X_gru [B,T]
#define XOUT_OFF 0
#define T10_OFF  (B_N * T_N)
#define M0_OFF   (T10_OFF + B_N)
#define OUT_OFF  (M0_OFF + B_N)
#define XGRU_OFF (OUT_OFF + B_N * T_N * H_N)

// ws layout (bytes)
#define WS_HIDT 0
#define WS_HIDM (WS_HIDT + B_N * 64 * 4)
#define WS_W1T_HI (WS_HIDM + B_N * 64 * 4)
#define WS_W1T_LO (WS_W1T_HI + 304 * 64 * 2)
#define WS_W1M_HI (WS_W1T_LO + 304 * 64 * 2)
#define WS_W1M_LO (WS_W1M_HI + 304 * 64 * 2)
#define WS_W2T_HI (WS_W1M_LO + 304 * 64 * 2)
#define WS_W2T_LO (WS_W2T_HI + 304 * 320 * 2)
#define WS_W2M_HI (WS_W2T_LO + 304 * 320 * 2)
#define WS_W2M_LO (WS_W2M_HI + 304 * 320 * 2)

typedef float  f32x4  __attribute__((ext_vector_type(4)));
typedef __bf16 bf16x8 __attribute__((ext_vector_type(8)));
typedef __bf16 bf16x4 __attribute__((ext_vector_type(4)));

__device__ __forceinline__ f32x4 mfma16(bf16x8 a, bf16x8 b, f32x4 c) {
  return __builtin_amdgcn_mfma_f32_16x16x32_bf16(a, b, c, 0, 0, 0);
}
__device__ __forceinline__ void split8v(const float* v, bf16x8& hi, bf16x8& lo) {
#pragma unroll
  for (int i = 0; i < 8; ++i) {
    __bf16 h = (__bf16)v[i];
    hi[i] = h;
    lo[i] = (__bf16)(v[i] - (float)h);
  }
}
__device__ __forceinline__ void split4v(const float* v, bf16x4& hi, bf16x4& lo) {
#pragma unroll
  for (int i = 0; i < 4; ++i) {
    __bf16 h = (__bf16)v[i];
    hi[i] = h;
    lo[i] = (__bf16)(v[i] - (float)h);
  }
}
__device__ __forceinline__ float sigm(float x) { return 1.f / (1.f + __expf(-x)); }
__device__ __forceinline__ float tanh_f(float x) { return 1.f - 2.f / (__expf(2.f * x) + 1.f); }

// ---------------------------------------------------------------------------
// K1: GRU-D scan + online attention pooling.
// 256 blocks x 256 thr; wave = 16 batch rows (lane&15 = row, lane>>4 = j-group).
// Orientation: out^T = W * h^T  => D-frag: lane owns (b = lane&15, j = 16*jt + 4*(lane>>4) + i)
// LDS map (bytes):
//   [0,16384)      W_hc hi bf16 [128][64], row stride 128B, swizzle byte^=(row&7)<<4
//   [16384,24576)  W_hn hi bf16 [64][64]
//   [24576,27392)  fp32 consts: Wgh[64] bgh[64] Wxc[192] Wmc[192] bxc[192]
//   [27392,43776)  per-wave h staging: wave w: hi @27392+w*4096, lo @+2048 ([16][64] bf16)
// ---------------------------------------------------------------------------
__global__ __launch_bounds__(256, 1) void k_gru(
    const float* __restrict__ Xfa, const float* __restrict__ Xlast,
    const float* __restrict__ Xmean, const float* __restrict__ Xmask,
    const float* __restrict__ Xdelta,
    const float* __restrict__ Wgx, const float* __restrict__ bgx,
    const float* __restrict__ Wgh, const float* __restrict__ bgh,
    const float* __restrict__ Wxc, const float* __restrict__ bxc,
    const float* __restrict__ Whn, const float* __restrict__ Whc,
    const float* __restrict__ Wmc,
    const float* __restrict__ WsT, const float* __restrict__ WsM,
    float* __restrict__ dout, float* __restrict__ hidT, float* __restrict__ hidM) {
  __shared__ __align__(16) unsigned char smem[43776];
  const int tid = threadIdx.x;
  const int wv = tid >> 6, l = tid & 63, b16 = l & 15, g4 = l >> 4;
  const int b = blockIdx.x * 64 + wv * 16 + b16;

  // ---- stage fp32 constants ----
  {
    float* cf = (float*)(smem + 24576);
    for (int i = tid; i < 704; i += 256) {
      float v;
      if (i < 64) v = Wgh[i];
      else if (i < 128) v = bgh[i - 64];
      else if (i < 320) v = Wxc[i - 128];
      else if (i < 512) v = Wmc[i - 320];
      else v = bxc[i - 512];
      cf[i] = v;
    }
  }
  // ---- stage W hi into LDS (redundant across waves; identical data), keep lo frags in regs ----
  bf16x8 whc_lo[8][2], whn_lo[4][2];
#pragma unroll
  for (int jt = 0; jt < 8; ++jt) {
#pragma unroll
    for (int kt = 0; kt < 2; ++kt) {
      const int row = jt * 16 + b16;
      const float* src = Whc + row * 64 + kt * 32 + g4 * 8;
      float v[8];
      *(float4*)&v[0] = *(const float4*)src;
      *(float4*)&v[4] = *(const float4*)(src + 4);
      bf16x8 hi, lo;
      split8v(v, hi, lo);
      whc_lo[jt][kt] = lo;
      *(bf16x8*)(smem + row * 128 + ((kt * 64 + g4 * 16) ^ ((row & 7) << 4))) = hi;
    }
  }
#pragma unroll
  for (int jt = 0; jt < 4; ++jt) {
#pragma unroll
    for (int kt = 0; kt < 2; ++kt) {
      const int row = jt * 16 + b16;
      const float* src = Whn + row * 64 + kt * 32 + g4 * 8;
      float v[8];
      *(float4*)&v[0] = *(const float4*)src;
      *(float4*)&v[4] = *(const float4*)(src + 4);
      bf16x8 hi, lo;
      split8v(v, hi, lo);
      whn_lo[jt][kt] = lo;
      *(bf16x8*)(smem + 16384 + row * 128 + ((kt * 64 + g4 * 16) ^ ((row & 7) << 4))) = hi;
    }
  }
  __syncthreads();

  const float* cWgh = (const float*)(smem + 24576);
  const float* cBgh = cWgh + 64;
  const float* cWxc = cWgh + 128;
  const float* cWmc = cWgh + 320;
  const float* cBxc = cWgh + 512;

  float wsTv[4][4], wsMv[4][4];
#pragma unroll
  for (int jt = 0; jt < 4; ++jt)
#pragma unroll
    for (int i = 0; i < 4; ++i) {
      const int j = jt * 16 + g4 * 4 + i;
      wsTv[jt][i] = WsT[j];
      wsMv[jt][i] = WsM[j];
    }

  float h[4][4] = {};
  float aT[4][4] = {}, aM[4][4] = {};
  float mT = -1e30f, lT = 0.f, mM = -1e30f, lM = 0.f;
  const float wgx0 = Wgx[0], bgx0 = bgx[0];

  const int ib = b * T_N;
  float p_xi = Xfa[ib], p_mm = Xmask[ib], p_dd = Xdelta[ib], p_xl = Xlast[ib], p_xm = Xmean[ib];
  const int hoff = 27392 + wv * 4096;  // hi; lo at +2048
  float* outp = dout + OUT_OFF;

  for (int t = 0; t < T_N; ++t) {
    const float xi = p_xi, mm = p_mm, dd = p_dd, xl = p_xl, xm = p_xm;
    const int tn = (t + 1 < T_N) ? t + 1 : T_N - 1;
    p_xi = Xfa[ib + tn]; p_mm = Xmask[ib + tn]; p_dd = Xdelta[ib + tn];
    p_xl = Xlast[ib + tn]; p_xm = Xmean[ib + tn];

    const float gx = __expf(-fmaxf(0.f, dd * wgx0 + bgx0));
    const float X = mm * xi + (1.f - mm) * gx * xl + (1.f - mm) * (1.f - gx) * xm;
    if (l < 16) dout[XGRU_OFF + ib + t] = X;

    // decay h and stage (hi/lo) to LDS
#pragma unroll
    for (int jt = 0; jt < 4; ++jt) {
      const int j0 = jt * 16 + g4 * 4;
      f32x4 wg = *(const f32x4*)(cWgh + j0);
      f32x4 bg = *(const f32x4*)(cBgh + j0);
      float v[4];
#pragma unroll
      for (int i = 0; i < 4; ++i) {
        const float ghv = __expf(-fmaxf(0.f, dd * wg[i] + bg[i]));
        h[jt][i] *= ghv;
        v[i] = h[jt][i];
      }
      bf16x4 hi4, lo4;
      split4v(v, hi4, lo4);
      const int off = (jt * 32 + g4 * 8) ^ ((b16 & 7) << 4);
      *(bf16x4*)(smem + hoff + b16 * 128 + off) = hi4;
      *(bf16x4*)(smem + hoff + 2048 + b16 * 128 + off) = lo4;
    }
    // B-fragments of h
    bf16x8 bh[2], bl[2];
#pragma unroll
    for (int kt = 0; kt < 2; ++kt) {
      const int off = (kt * 64 + g4 * 16) ^ ((b16 & 7) << 4);
      bh[kt] = *(const bf16x8*)(smem + hoff + b16 * 128 + off);
      bl[kt] = *(const bf16x8*)(smem + hoff + 2048 + b16 * 128 + off);
    }
    // G1: z,r pre-activations (compensated 3-term)
    f32x4 accZ[4], accR[4];
#pragma unroll
    for (int jt = 0; jt < 8; ++jt) {
      f32x4 acc = {0.f, 0.f, 0.f, 0.f};
#pragma unroll
      for (int kt = 0; kt < 2; ++kt) {
        const int row = jt * 16 + b16;
        bf16x8 ahi = *(const bf16x8*)(smem + row * 128 + ((kt * 64 + g4 * 16) ^ ((row & 7) << 4)));
        acc = mfma16(ahi, bh[kt], acc);
        acc = mfma16(whc_lo[jt][kt], bh[kt], acc);
        acc = mfma16(ahi, bl[kt], acc);
      }
      if (jt < 4) accZ[jt] = acc; else accR[jt - 4] = acc;
    }
    // gates z,r ; stage r*h
    float zz[4][4];
#pragma unroll
    for (int jt = 0; jt < 4; ++jt) {
      const int j0 = jt * 16 + g4 * 4;
      f32x4 cwz = *(const f32x4*)(cWxc + j0);
      f32x4 cbz = *(const f32x4*)(cBxc + j0);
      f32x4 cmz = *(const f32x4*)(cWmc + j0);
      f32x4 cwr = *(const f32x4*)(cWxc + 64 + j0);
      f32x4 cbr = *(const f32x4*)(cBxc + 64 + j0);
      f32x4 cmr = *(const f32x4*)(cWmc + 64 + j0);
      float v[4];
#pragma unroll
      for (int i = 0; i < 4; ++i) {
        const float z = sigm(accZ[jt][i] + X * cwz[i] + cbz[i] + mm * cmz[i]);
        const float r = sigm(accR[jt][i] + X * cwr[i] + cbr[i] + mm * cmr[i]);
        zz[jt][i] = z;
        v[i] = r * h[jt][i];
      }
      bf16x4 hi4, lo4;
      split4v(v, hi4, lo4);
      const int off = (jt * 32 + g4 * 8) ^ ((b16 & 7) << 4);
      *(bf16x4*)(smem + hoff + b16 * 128 + off) = hi4;
      *(bf16x4*)(smem + hoff + 2048 + b16 * 128 + off) = lo4;
    }
    bf16x8 ch[2], cl[2];
#pragma unroll
    for (int kt = 0; kt < 2; ++kt) {
      const int off = (kt * 64 + g4 * 16) ^ ((b16 & 7) << 4);
      ch[kt] = *(const bf16x8*)(smem + hoff + b16 * 128 + off);
      cl[kt] = *(const bf16x8*)(smem + hoff + 2048 + b16 * 128 + off);
    }
    // G2: (r*h) @ W_hn^T
    f32x4 accN[4];
#pragma unroll
    for (int jt = 0; jt < 4; ++jt) {
      f32x4 acc = {0.f, 0.f, 0.f, 0.f};
#pragma unroll
      for (int kt = 0; kt < 2; ++kt) {
        const int row = jt * 16 + b16;
        bf16x8 ahi =
            *(const bf16x8*)(smem + 16384 + row * 128 + ((kt * 64 + g4 * 16) ^ ((row & 7) << 4)));
        acc = mfma16(ahi, ch[kt], acc);
        acc = mfma16(whn_lo[jt][kt], ch[kt], acc);
        acc = mfma16(ahi, cl[kt], acc);
      }
      accN[jt] = acc;
    }
    // update h, store out, attention scores
    float scT = 0.f, scM = 0.f;
#pragma unroll
    for (int jt = 0; jt < 4; ++jt) {
      const int j0 = jt * 16 + g4 * 4;
      f32x4 cwn = *(const f32x4*)(cWxc + 128 + j0);
      f32x4 cbn = *(const f32x4*)(cBxc + 128 + j0);
      f32x4 cmn = *(const f32x4*)(cWmc + 128 + j0);
      f32x4 ho;
#pragma unroll
      for (int i = 0; i < 4; ++i) {
        const float pre = accN[jt][i] + X * cwn[i] + cbn[i] + mm * cmn[i];
        const float ht = tanh_f(pre);
        const float hn = (1.f - zz[jt][i]) * h[jt][i] + zz[jt][i] * ht;
        h[jt][i] = hn;
        ho[i] = hn;
        scT += hn * wsTv[jt][i];
        scM += hn * wsMv[jt][i];
      }
      *(f32x4*)(outp + (ib + t) * 64 + j0) = ho;
    }
    scT += __shfl_xor(scT, 16); scT += __shfl_xor(scT, 32);
    scM += __shfl_xor(scM, 16); scM += __shfl_xor(scM, 32);
    {
      const float mn = fmaxf(mT, scT);
      const float s = __expf(mT - mn), p = __expf(scT - mn);
      lT = lT * s + p;
#pragma unroll
      for (int jt = 0; jt < 4; ++jt)
#pragma unroll
        for (int i = 0; i < 4; ++i) aT[jt][i] = aT[jt][i] * s + p * h[jt][i];
      mT = mn;
    }
    {
      const float mn = fmaxf(mM, scM);
      const float s = __expf(mM - mn), p = __expf(scM - mn);
      lM = lM * s + p;
#pragma unroll
      for (int jt = 0; jt < 4; ++jt)
#pragma unroll
        for (int i = 0; i < 4; ++i) aM[jt][i] = aM[jt][i] * s + p * h[jt][i];
      mM = mn;
    }
  }
  const float invT = 1.f / lT, invM = 1.f / lM;
#pragma unroll
  for (int jt = 0; jt < 4; ++jt) {
    const int j0 = jt * 16 + g4 * 4;
    f32x4 vT, vM;
#pragma unroll
    for (int i = 0; i < 4; ++i) { vT[i] = aT[jt][i] * invT; vM[i] = aM[jt][i] * invM; }
    *(f32x4*)(hidT + b * 64 + j0) = vT;
    *(f32x4*)(hidM + b * 64 + j0) = vM;
  }
}

// ---------------------------------------------------------------------------
// K0: split MLP weights into bf16 hi/lo with zero padding (W1:[304][64], W2:[304][320])
// ---------------------------------------------------------------------------
__device__ __forceinline__ void wsplit(float v, unsigned short* hi, unsigned short* lo, int idx) {
  union { __bf16 b; unsigned short u; } c;
  __bf16 hb = (__bf16)v;
  c.b = hb; hi[idx] = c.u;
  c.b = (__bf16)(v - (float)hb); lo[idx] = c.u;
}
__global__ void k_prep(const float* __restrict__ Wt1, const float* __restrict__ Wm1,
                       const float* __restrict__ Wt2, const float* __restrict__ Wm2,
                       unsigned short* w1t_hi, unsigned short* w1t_lo,
                       unsigned short* w1m_hi, unsigned short* w1m_lo,
                       unsigned short* w2t_hi, unsigned short* w2t_lo,
                       unsigned short* w2m_hi, unsigned short* w2m_lo) {
  const int i = blockIdx.x * 256 + threadIdx.x;  // grid covers exactly 304*320
  if (i < 304 * 64) {
    const int r = i >> 6, c = i & 63;
    const float vt = (r < 300) ? Wt1[r * 64 + c] : 0.f;
    const float vm = (r < 300) ? Wm1[r * 64 + c] : 0.f;
    wsplit(vt, w1t_hi, w1t_lo, i);
    wsplit(vm, w1m_hi, w1m_lo, i);
  }
  {
    const int r = i / 320, c = i - r * 320;
    const bool ok = (r < 300) && (c < 300);
    const float vt = ok ? Wt2[r * 300 + c] : 0.f;
    const float vm = ok ? Wm2[r * 300 + c] : 0.f;
    wsplit(vt, w2t_hi, w2t_lo, i);
    wsplit(vm, w2m_hi, w2m_lo, i);
  }
}

// ---------------------------------------------------------------------------
// K2: MLP head. 512 blocks: [0,256) T-path, [256,512) M-path. 64 rows/block.
// LDS: h1buf 4 waves x [16][320] bf16 (row 640B, swizzled) @0..40960;
//      sb1 @40960, sb2 @42176, sw3 @43392 (304 floats each)
// ---------------------------------------------------------------------------
__global__ __launch_bounds__(256, 2) void k_mlp(
    const float* __restrict__ hidT, const float* __restrict__ hidM,
    const unsigned short* __restrict__ w1t_hi, const unsigned short* __restrict__ w1t_lo,
    const unsigned short* __restrict__ w1m_hi, const unsigned short* __restrict__ w1m_lo,
    const unsigned short* __restrict__ w2t_hi, const unsigned short* __restrict__ w2t_lo,
    const unsigned short* __restrict__ w2m_hi, const unsigned short* __restrict__ w2m_lo,
    const float* __restrict__ bt1, const float* __restrict__ bt2,
    const float* __restrict__ Wt3, const float* __restrict__ bt3,
    const float* __restrict__ bm1, const float* __restrict__ bm2,
    const float* __restrict__ Wm3, const float* __restrict__ bm3,
    float* __restrict__ dout) {
  __shared__ __align__(16) unsigned char smem[44608];
  const int tid = threadIdx.x;
  const int blk = blockIdx.x & 255;
  const bool isM = blockIdx.x >= 256;
  const float* hid = isM ? hidM : hidT;
  const unsigned short* w1hi = isM ? w1m_hi : w1t_hi;
  const unsigned short* w1lo = isM ? w1m_lo : w1t_lo;
  const unsigned short* w2hi = isM ? w2m_hi : w2t_hi;
  const unsigned short* w2lo = isM ? w2m_lo : w2t_lo;
  const float* b1 = isM ? bm1 : bt1;
  const float* b2 = isM ? bm2 : bt2;
  const float* w3 = isM ? Wm3 : Wt3;
  const float b3 = (isM ? bm3 : bt3)[0];
  const float LOV = isM ? 0.1f : 0.2f;
  const float HIV = isM ? 20.f : 5.0f;
  float* headp = dout + (isM ? M0_OFF : T10_OFF);

  float* sb1 = (float*)(smem + 40960);
  float* sb2 = (float*)(smem + 42176);
  float* sw3 = (float*)(smem + 43392);
  for (int i = tid; i < 304; i += 256) {
    sb1[i] = (i < 300) ? b1[i] : 0.f;
    sb2[i] = (i < 300) ? b2[i] : 0.f;
    sw3[i] = (i < 300) ? w3[i] : 0.f;
  }
  __syncthreads();

  const int wv = tid >> 6, l = tid & 63, b16 = l & 15, g4 = l >> 4;
  const int b = blk * 64 + wv * 16 + b16;
  const int h1off = wv * 10240;

  // L1: hid -> 304 (3-term compensated)
  bf16x8 b1h[2], b1l[2];
#pragma unroll
  for (int kt = 0; kt < 2; ++kt) {
    const float* hp = hid + b * 64 + kt * 32 + g4 * 8;
    float v[8];
    *(float4*)&v[0] = *(const float4*)hp;
    *(float4*)&v[4] = *(const float4*)(hp + 4);
    split8v(v, b1h[kt], b1l[kt]);
  }
  f32x4 acc1[19];
#pragma unroll
  for (int jt = 0; jt < 19; ++jt) {
    f32x4 acc = {0.f, 0.f, 0.f, 0.f};
#pragma unroll
    for (int kt = 0; kt < 2; ++kt) {
      const int row = jt * 16 + b16;
      bf16x8 ahi = *(const bf16x8*)(w1hi + row * 64 + kt * 32 + g4 * 8);
      bf16x8 alo = *(const bf16x8*)(w1lo + row * 64 + kt * 32 + g4 * 8);
      acc = mfma16(ahi, b1h[kt], acc);
      acc = mfma16(alo, b1h[kt], acc);
      acc = mfma16(ahi, b1l[kt], acc);
    }
    acc1[jt] = acc;
  }
  // zero k-pad cols [304,320) of own rows (pre-swizzle offsets [608,640))
  if (g4 == 0) {
#pragma unroll
    for (int q = 0; q < 4; ++q) {
      const int off = (608 + q * 8) ^ ((b16 & 7) << 4);
      *(unsigned long long*)(smem + h1off + b16 * 640 + off) = 0ull;
    }
  }
  // bias + ELU -> stage h1 (bf16) in swizzled LDS
#pragma unroll
  for (int jt = 0; jt < 19; ++jt) {
    bf16x4 hv;
#pragma unroll
    for (int i = 0; i < 4; ++i) {
      const int j = jt * 16 + g4 * 4 + i;
      const float v = acc1[jt][i] + sb1[j];
      const float e = (v > 0.f) ? v : (__expf(v) - 1.f);
      hv[i] = (__bf16)e;
    }
    const int off = (jt * 32 + g4 * 8) ^ ((b16 & 7) << 4);
    *(bf16x4*)(smem + h1off + b16 * 640 + off) = hv;
  }
  // L2 (2-term) with fused L3 dot
  bf16x8 bh2[10];
#pragma unroll
  for (int kt = 0; kt < 10; ++kt) {
    const int off = (kt * 64 + g4 * 16) ^ ((b16 & 7) << 4);
    bh2[kt] = *(const bf16x8*)(smem + h1off + b16 * 640 + off);
  }
  float raw = 0.f;
#pragma unroll
  for (int jt = 0; jt < 19; ++jt) {
    f32x4 acc = {0.f, 0.f, 0.f, 0.f};
#pragma unroll
    for (int kt = 0; kt < 10; ++kt) {
      const int row = jt * 16 + b16;
      bf16x8 ahi = *(const bf16x8*)(w2hi + row * 320 + kt * 32 + g4 * 8);
      bf16x8 alo = *(const bf16x8*)(w2lo + row * 320 + kt * 32 + g4 * 8);
      acc = mfma16(ahi, bh2[kt], acc);
      acc = mfma16(alo, bh2[kt], acc);
    }
#pragma unroll
    for (int i = 0; i < 4; ++i) {
      const int j = jt * 16 + g4 * 4 + i;
      const float v = acc[i] + sb2[j];
      const float e = (v > 0.f) ? v : (__expf(v) - 1.f);
      raw += e * sw3[j];
    }
  }
  raw += __shfl_xor(raw, 16);
  raw += __shfl_xor(raw, 32);
  if (l < 16) {
    const float rr = raw + b3;
    headp[b] = LOV + (HIV - LOV) / (1.f + __expf(-rr));
  }
}

// ---------------------------------------------------------------------------
// K3: X_out epilogue
// ---------------------------------------------------------------------------
__global__ void k_final(const float* __restrict__ fav, const float* __restrict__ TR,
                        float* __restrict__ dout) {
  const int i = blockIdx.x * 256 + threadIdx.x;  // < B*T
  const int bb = i >> 6;
  const float T10v = dout[T10_OFF + bb];
  const float M0v = dout[M0_OFF + bb];
  const float e = __expf(-TR[bb] / T10v);
  const float fa = fav[i];
  float s, c;
  __sincosf(fa, &s, &c);
  dout[i] = (1.f - e) * s / (1.f - c * e) * M0v;
}

// ---------------------------------------------------------------------------
extern "C" void kernel_launch(void* const* d_in, const int* in_sizes, int n_in,
                              void* d_out, int out_size, void* d_ws, size_t ws_size,
                              hipStream_t stream) {
  const float* Xfa   = (const float*)d_in[0];
  const float* Xlast = (const float*)d_in[1];
  const float* Xmean = (const float*)d_in[2];
  const float* Xmask = (const float*)d_in[3];
  const float* Xdelta= (const float*)d_in[4];
  const float* fav   = (const float*)d_in[5];
  const float* TR    = (const float*)d_in[6];
  const float* Wgx   = (const float*)d_in[7];
  const float* bgx   = (const float*)d_in[8];
  const float* Wgh   = (const float*)d_in[9];
  const float* bgh   = (const float*)d_in[10];
  const float* Wxc   = (const float*)d_in[11];
  const float* bxc   = (const float*)d_in[12];
  const float* Whn   = (const float*)d_in[13];
  const float* Whc   = (const float*)d_in[14];
  const float* Wmc   = (const float*)d_in[15];
  const float* WsT   = (const float*)d_in[16];
  const float* WsM   = (const float*)d_in[17];
  const float* Wt1   = (const float*)d_in[18];
  const float* bt1   = (const float*)d_in[19];
  const float* Wt2   = (const float*)d_in[20];
  const float* bt2   = (const float*)d_in[21];
  const float* Wt3   = (const float*)d_in[22];
  const float* bt3   = (const float*)d_in[23];
  const float* Wm1   = (const float*)d_in[24];
  const float* bm1   = (const float*)d_in[25];
  const float* Wm2   = (const float*)d_in[26];
  const float* bm2   = (const float*)d_in[27];
  const float* Wm3   = (const float*)d_in[28];
  const float* bm3   = (const float*)d_in[29];

  float* dout = (float*)d_out;
  char* ws = (char*)d_ws;
  float* hidT = (float*)(ws + WS_HIDT);
  float* hidM = (float*)(ws + WS_HIDM);
  unsigned short* w1t_hi = (unsigned short*)(ws + WS_W1T_HI);
  unsigned short* w1t_lo = (unsigned short*)(ws + WS_W1T_LO);
  unsigned short* w1m_hi = (unsigned short*)(ws + WS_W1M_HI);
  unsigned short* w1m_lo = (unsigned short*)(ws + WS_W1M_LO);
  unsigned short* w2t_hi = (unsigned short*)(ws + WS_W2T_HI);
  unsigned short* w2t_lo = (unsigned short*)(ws + WS_W2T_LO);
  unsigned short* w2m_hi = (unsigned short*)(ws + WS_W2M_HI);
  unsigned short* w2m_lo = (unsigned short*)(ws + WS_W2M_LO);

  k_prep<<<380, 256, 0, stream>>>(Wt1, Wm1, Wt2, Wm2, w1t_hi, w1t_lo, w1m_hi, w1m_lo,
                                  w2t_hi, w2t_lo, w2m_hi, w2m_lo);
  k_gru<<<256, 256, 0, stream>>>(Xfa, Xlast, Xmean, Xmask, Xdelta, Wgx, bgx, Wgh, bgh, Wxc, bxc,
                                 Whn, Whc, Wmc, WsT, WsM, dout, hidT, hidM);
  k_mlp<<<512, 256, 0, stream>>>(hidT, hidM, w1t_hi, w1t_lo, w1m_hi, w1m_lo, w2t_hi, w2t_lo,
                                 w2m_hi, w2m_lo, bt1, bt2, Wt3, bt3, bm1, bm2, Wm3, bm3, dout);
  k_final<<<4096, 256, 0, stream>>>(fav, TR, dout);
}